// Round 4
// baseline (126.692 us; speedup 1.0000x reference)
//
#include <hip/hip_runtime.h>
#include <math.h>

typedef _Float16 f16;
typedef __attribute__((ext_vector_type(8))) _Float16 f16x8;
typedef __attribute__((ext_vector_type(4))) _Float16 f16x4;
typedef __attribute__((ext_vector_type(4))) float f32x4;

constexpr int BATCH = 32;
constexpr int QL = 1024;
constexpr int KL = 1024;
constexpr int D = 128;
constexpr int BQ = 128;   // query rows per block (32 per wave, 2 halves of 16)
constexpr int BK = 64;    // key rows per tile
constexpr int DKP = 136;  // sK row pitch in halves (272 B; 272%128=16 -> bank-spread)
constexpr int BKP = 72;   // sVT row pitch in halves (144 B; 144%128=16 -> bank-spread)

// scale * log2(e): softmax in exp2 domain; folded into Q fragments at load.
#define CSC 0.12752863187087177f

static __device__ __forceinline__ f16x4 pk4(float x, float y, float z, float w) {
  auto a = __builtin_amdgcn_cvt_pkrtz(x, y);
  auto b = __builtin_amdgcn_cvt_pkrtz(z, w);
  f16x4 h;
  h[0] = (f16)a[0]; h[1] = (f16)a[1]; h[2] = (f16)b[0]; h[3] = (f16)b[1];
  return h;
}
static __device__ __forceinline__ f16x8 pk8(float4 u, float4 v) {
  f16x4 a = pk4(u.x, u.y, u.z, u.w);
  f16x4 b = pk4(v.x, v.y, v.z, v.w);
  f16x8 h;
  h[0] = a[0]; h[1] = a[1]; h[2] = a[2]; h[3] = a[3];
  h[4] = b[0]; h[5] = b[1]; h[6] = b[2]; h[7] = b[3];
  return h;
}
// pack two f32x4 (P values) to f16x8
static __device__ __forceinline__ f16x8 pk8v(f32x4 a, f32x4 b) {
  auto x0 = __builtin_amdgcn_cvt_pkrtz(a[0], a[1]);
  auto x1 = __builtin_amdgcn_cvt_pkrtz(a[2], a[3]);
  auto x2 = __builtin_amdgcn_cvt_pkrtz(b[0], b[1]);
  auto x3 = __builtin_amdgcn_cvt_pkrtz(b[2], b[3]);
  f16x8 h;
  h[0] = x0[0]; h[1] = x0[1]; h[2] = x1[0]; h[3] = x1[1];
  h[4] = x2[0]; h[5] = x2[1]; h[6] = x3[0]; h[7] = x3[1];
  return h;
}
// pack Q with CSC folded in (one f16 rounding, same as before -> same error)
static __device__ __forceinline__ f16x8 pk8s(float4 u, float4 v) {
  float4 a = {u.x * CSC, u.y * CSC, u.z * CSC, u.w * CSC};
  float4 b = {v.x * CSC, v.y * CSC, v.z * CSC, v.w * CSC};
  return pk8(a, b);
}

// ---- staging-row permutation for sK.
// Swapped QK^T (A = K) needs MFMA ct, A-position p = l16 to hold actual key
//   key(ct,p) = (ct>>1)*32 + (p>>2)*8 + (ct&1)*4 + (p&3)
// so that sv[ct][r] at lane(quad) is key = (ct>>1)*32 + quad*8 + (ct&1)*4 + r,
// which is EXACTLY the PV B-operand k-layout (pf[ks] = keys ks*32+quad*8+0..7).
// Inverse (actual key kk -> LDS row):
static __device__ __forceinline__ int krp(int kk) {
  return ((kk >> 5) << 5) | (((kk >> 2) & 1) << 4) | (((kk >> 3) & 3) << 2) | (kk & 3);
}

// ---- issue global loads for tile T into reg set (KR,VR)
#define ISSUE(KR, VR, T)                                                   \
  do {                                                                     \
    const float4* Kt = (const float4*)(Kb + (size_t)(T) * BK * D);         \
    _Pragma("unroll")                                                      \
    for (int i_ = 0; i_ < 4; ++i_) {                                       \
      int cc_ = tid + i_ * 256;                                            \
      int row_ = cc_ >> 4, d04_ = (cc_ & 15) * 2;                          \
      KR[2 * i_]     = Kt[row_ * 32 + d04_];                               \
      KR[2 * i_ + 1] = Kt[row_ * 32 + d04_ + 1];                           \
    }                                                                      \
    const float* Vt = Vb + (size_t)(T) * BK * D;                           \
    _Pragma("unroll")                                                      \
    for (int i_ = 0; i_ < 2; ++i_) {                                       \
      int f_ = tid + i_ * 256;                                             \
      const float* base_ = Vt + (size_t)((f_ & 15) * 4) * D + (f_ >> 4) * 4; \
      VR[i_ * 4 + 0] = *(const float4*)(base_);                            \
      VR[i_ * 4 + 1] = *(const float4*)(base_ + D);                        \
      VR[i_ * 4 + 2] = *(const float4*)(base_ + 2 * D);                    \
      VR[i_ * 4 + 3] = *(const float4*)(base_ + 3 * D);                    \
    }                                                                      \
  } while (0)

// ---- convert+store reg set into LDS buffer NB
#define DRAIN(KR, VR, NB)                                                  \
  do {                                                                     \
    _Pragma("unroll")                                                      \
    for (int i_ = 0; i_ < 4; ++i_) {                                       \
      int cc_ = tid + i_ * 256;                                            \
      int row_ = cc_ >> 4, d0_ = (cc_ & 15) * 8;                           \
      *(f16x8*)&sK[NB][krp(row_)][d0_] = pk8(KR[2 * i_], KR[2 * i_ + 1]);  \
    }                                                                      \
    _Pragma("unroll")                                                      \
    for (int i_ = 0; i_ < 2; ++i_) {                                       \
      int f_ = tid + i_ * 256;                                             \
      int k0_ = (f_ & 15) * 4, d0_ = (f_ >> 4) * 4;                        \
      float4 r0_ = VR[i_*4+0], r1_ = VR[i_*4+1], r2_ = VR[i_*4+2], r3_ = VR[i_*4+3]; \
      *(f16x4*)&sVT[NB][d0_ + 0][k0_] = pk4(r0_.x, r1_.x, r2_.x, r3_.x);   \
      *(f16x4*)&sVT[NB][d0_ + 1][k0_] = pk4(r0_.y, r1_.y, r2_.y, r3_.y);   \
      *(f16x4*)&sVT[NB][d0_ + 2][k0_] = pk4(r0_.z, r1_.z, r2_.z, r3_.z);   \
      *(f16x4*)&sVT[NB][d0_ + 3][k0_] = pk4(r0_.w, r1_.w, r2_.w, r3_.w);   \
    }                                                                      \
  } while (0)

// raw barrier: lgkmcnt(0) for LDS visibility, NO forced vmcnt(0) drain
#define TILE_BARRIER()                                                     \
  do {                                                                     \
    asm volatile("s_waitcnt lgkmcnt(0)" ::: "memory");                     \
    __builtin_amdgcn_s_barrier();                                          \
    asm volatile("" ::: "memory");                                         \
  } while (0)

// ---- online softmax for one q-half, fully in-register.
// SV = f32x4[4] (S^T values: q=l16, key=(ct>>1)*32+quad*8+(ct&1)*4+r),
// MM/LL = running max/sum (scalar per lane), PF = f16x8[2] out, OO = f32x4[8] acc.
#define SOFTMAX_HALF(SV, MM, LL, PF, OO)                                   \
  do {                                                                     \
    float t0_ = fmaxf(fmaxf(SV[0][0], SV[0][1]), fmaxf(SV[0][2], SV[0][3]));\
    float t1_ = fmaxf(fmaxf(SV[1][0], SV[1][1]), fmaxf(SV[1][2], SV[1][3]));\
    float t2_ = fmaxf(fmaxf(SV[2][0], SV[2][1]), fmaxf(SV[2][2], SV[2][3]));\
    float t3_ = fmaxf(fmaxf(SV[3][0], SV[3][1]), fmaxf(SV[3][2], SV[3][3]));\
    float pmax_ = fmaxf(fmaxf(t0_, t1_), fmaxf(t2_, t3_));                 \
    pmax_ = fmaxf(pmax_, __shfl_xor(pmax_, 16));                           \
    pmax_ = fmaxf(pmax_, __shfl_xor(pmax_, 32));                           \
    float mnew_  = fmaxf(MM, pmax_);                                       \
    float alpha_ = __builtin_amdgcn_exp2f(MM - mnew_);                     \
    MM = mnew_;                                                            \
    float ls_ = 0.f;                                                       \
    _Pragma("unroll")                                                      \
    for (int ct_ = 0; ct_ < 4; ++ct_) {                                    \
      _Pragma("unroll")                                                    \
      for (int r_ = 0; r_ < 4; ++r_) {                                     \
        float p_ = __builtin_amdgcn_exp2f(SV[ct_][r_] - mnew_);            \
        SV[ct_][r_] = p_;                                                  \
        ls_ += p_;                                                         \
      }                                                                    \
    }                                                                      \
    ls_ += __shfl_xor(ls_, 16);                                            \
    ls_ += __shfl_xor(ls_, 32);                                            \
    LL = LL * alpha_ + ls_;                                                \
    PF[0] = pk8v(SV[0], SV[1]);                                            \
    PF[1] = pk8v(SV[2], SV[3]);                                            \
    _Pragma("unroll")                                                      \
    for (int dt_ = 0; dt_ < 8; ++dt_) OO[dt_] *= alpha_;                   \
  } while (0)

__global__ __launch_bounds__(256, 1)
void attn_fwd(const float* __restrict__ Qp, const float* __restrict__ Kp,
              const float* __restrict__ Vp, const int* __restrict__ VLp,
              float* __restrict__ Op) {
  // R3 post-mortem: kernel was LDS-pipe bound (2 blocks/CU x 4 waves each
  // reading full 32KB K+V tiles for only 16 q-rows/wave ~= 5.5k LDS-cyc/tile
  // = measured 7k cyc/tile). Fix: 32 q-rows/wave (every kf/vf read feeds 2
  // MFMAs), 1 block/CU, and NO P LDS round-trip (double operand swap).
  __shared__ f16 sK[2][BK][DKP];   // ROW-PERMUTED per krp() for swapped QK^T
  __shared__ f16 sVT[2][D][BKP];   // V tile transposed [d][kk]
  __shared__ int sN[32];
  __shared__ int sI[32];           // cost-rank -> batch

  const int tid  = threadIdx.x;
  const int wave = tid >> 6, lane = tid & 63;
  const int l16  = lane & 15, quad = lane >> 4;

  // ---- XCD-bound schedule (VERIFIED R1/R3: FETCH 81->17 MB).
  // 256 blocks: XCD = id&7 (round-robin), 32 blocks/XCD = 1/CU.
  // Each XCD owns 4 batches by cost-rank {x, 15-x, 16+x, 31-x}; 8 qt-blocks
  // each -> per-XCD K/V working set ~2-4 MB stays in its 4 MB L2.
  if (tid < 32) sN[tid] = (VLp[tid] + BK - 1) / BK;
  __syncthreads();
  if (tid < 32) {
    int nb = sN[tid], r = 0;
    #pragma unroll
    for (int k = 0; k < 32; ++k) {
      int nk = sN[k];
      r += (nk > nb) || (nk == nb && k < tid);
    }
    sI[r] = tid;  // invert: rank -> batch
  }
  __syncthreads();
  const int xcd = blockIdx.x & 7;
  const int j   = (int)blockIdx.x >> 3;  // 0..31 within XCD
  const int lr  = j >> 3;                // rank slot 0..3
  const int qt  = j & 7;                 // q-tile 0..7 (BQ=128)
  const int grank = (lr == 0) ? xcd : (lr == 1) ? (15 - xcd)
                  : (lr == 2) ? (16 + xcd) : (31 - xcd);
  const int b  = sI[grank];
  const int vl = VLp[b];

  const float* Kb = Kp + (size_t)b * KL * D;
  const float* Vb = Vp + (size_t)b * KL * D;
  const int ntiles = (vl + BK - 1) / BK;

  float4 kreg[8], vreg[8];

  // Q loads first (oldest in vmcnt order): converting qfrag waits only these.
  const float* Qb = Qp + ((size_t)(b * QL + qt * BQ + wave * 32 + l16)) * D;
  float4 qtmp[16];
  #pragma unroll
  for (int h = 0; h < 2; ++h)
    #pragma unroll
    for (int kc = 0; kc < 4; ++kc) {
      const float* p = Qb + h * 16 * D + kc * 32 + quad * 8;
      qtmp[h * 8 + 2 * kc]     = *(const float4*)p;
      qtmp[h * 8 + 2 * kc + 1] = *(const float4*)(p + 4);
    }

  ISSUE(kreg, vreg, 0);

  // Q as B-operand fragments (col=q=l16, k=quad*8+j), CSC pre-folded.
  f16x8 qf0[4], qf1[4];
  #pragma unroll
  for (int kc = 0; kc < 4; ++kc)
    qf0[kc] = pk8s(qtmp[2 * kc], qtmp[2 * kc + 1]);
  #pragma unroll
  for (int kc = 0; kc < 4; ++kc)
    qf1[kc] = pk8s(qtmp[8 + 2 * kc], qtmp[8 + 2 * kc + 1]);

  float m0 = -INFINITY, m1 = -INFINITY;
  float l0 = 0.f, l1 = 0.f;
  f32x4 o0[8], o1[8];
  #pragma unroll
  for (int dt = 0; dt < 8; ++dt) {
    o0[dt] = (f32x4){0.f, 0.f, 0.f, 0.f};
    o1[dt] = (f32x4){0.f, 0.f, 0.f, 0.f};
  }

  DRAIN(kreg, vreg, 0);
  TILE_BARRIER();

  for (int t = 0; t < ntiles; ++t) {
    const int cur = t & 1, nxt = cur ^ 1;
    const bool more = (t + 1 < ntiles);

    if (more) ISSUE(kreg, vreg, t + 1);

    // ---- S^T = K Q^T : each kf read feeds BOTH q-halves (2 MFMAs/read)
    f32x4 s0[4], s1[4];
    #pragma unroll
    for (int ct = 0; ct < 4; ++ct) {
      s0[ct] = (f32x4){0.f, 0.f, 0.f, 0.f};
      s1[ct] = (f32x4){0.f, 0.f, 0.f, 0.f};
      #pragma unroll
      for (int kc = 0; kc < 4; ++kc) {
        f16x8 kf = *(const f16x8*)&sK[cur][ct * 16 + l16][kc * 32 + quad * 8];
        s0[ct] = __builtin_amdgcn_mfma_f32_16x16x32_f16(kf, qf0[kc], s0[ct], 0, 0, 0);
        s1[ct] = __builtin_amdgcn_mfma_f32_16x16x32_f16(kf, qf1[kc], s1[ct], 0, 0, 0);
      }
    }

    // ---- key-padding mask, only on the (single) partial tile.
    // lane's key for (ct,r): t*64 + (ct>>1)*32 + (ct&1)*4 + quad*8 + r
    if (t * BK + BK > vl) {
      #pragma unroll
      for (int ct = 0; ct < 4; ++ct) {
        int kb = t * BK + (ct >> 1) * 32 + (ct & 1) * 4 + quad * 8;
        #pragma unroll
        for (int r = 0; r < 4; ++r) {
          bool ok = (kb + r) < vl;
          s0[ct][r] = ok ? s0[ct][r] : -1.0e9f;
          s1[ct][r] = ok ? s1[ct][r] : -1.0e9f;
        }
      }
    }

    // ---- online softmax, in-register (no P LDS round-trip, no lgkmcnt)
    f16x8 pf0[2], pf1[2];
    SOFTMAX_HALF(s0, m0, l0, pf0, o0);
    SOFTMAX_HALF(s1, m1, l1, pf1, o1);

    // ---- O^T += V^T P^T : each vf read feeds BOTH q-halves
    #pragma unroll
    for (int ks = 0; ks < 2; ++ks) {
      #pragma unroll
      for (int dt = 0; dt < 8; ++dt) {
        f16x8 vf = *(const f16x8*)&sVT[cur][dt * 16 + l16][ks * 32 + quad * 8];
        o0[dt] = __builtin_amdgcn_mfma_f32_16x16x32_f16(vf, pf0[ks], o0[dt], 0, 0, 0);
        o1[dt] = __builtin_amdgcn_mfma_f32_16x16x32_f16(vf, pf1[ks], o1[dt], 0, 0, 0);
      }
    }

    if (more) DRAIN(kreg, vreg, nxt);
    TILE_BARRIER();
  }

  // ---- epilogue: O = O^T/l. Lane holds O^T[d=dt*16+quad*4+r][q=h*16+l16];
  // the 4 r-values are CONTIGUOUS d -> float4 store (64B/row segments).
  float* Ob = Op + ((size_t)(b * QL + qt * BQ + wave * 32)) * D;
  const float inv0 = 1.0f / l0, inv1 = 1.0f / l1;
  #pragma unroll
  for (int dt = 0; dt < 8; ++dt) {
    float4 w0 = {o0[dt][0] * inv0, o0[dt][1] * inv0, o0[dt][2] * inv0, o0[dt][3] * inv0};
    float4 w1 = {o1[dt][0] * inv1, o1[dt][1] * inv1, o1[dt][2] * inv1, o1[dt][3] * inv1};
    *(float4*)&Ob[(size_t)l16 * D + dt * 16 + quad * 4]        = w0;
    *(float4*)&Ob[(size_t)(16 + l16) * D + dt * 16 + quad * 4] = w1;
  }
}

extern "C" void kernel_launch(void* const* d_in, const int* in_sizes, int n_in,
                              void* d_out, int out_size, void* d_ws, size_t ws_size,
                              hipStream_t stream) {
  const float* Qp = (const float*)d_in[0];
  const float* Kp = (const float*)d_in[1];
  const float* Vp = (const float*)d_in[2];
  const int*   VL = (const int*)d_in[3];
  float* Op = (float*)d_out;

  attn_fwd<<<dim3(QL / BQ * BATCH), dim3(256), 0, stream>>>(Qp, Kp, Vp, VL, Op);
}

// Round 5
// 115.944 us; speedup vs baseline: 1.0927x; 1.0927x over previous
//
#include <hip/hip_runtime.h>
#include <math.h>

typedef _Float16 f16;
typedef __attribute__((ext_vector_type(8))) _Float16 f16x8;
typedef __attribute__((ext_vector_type(4))) _Float16 f16x4;
typedef __attribute__((ext_vector_type(4))) float f32x4;

constexpr int BATCH = 32;
constexpr int QL = 1024;
constexpr int KL = 1024;
constexpr int D = 128;
constexpr int BQ = 64;    // query rows per block (16 per wave)
constexpr int BK = 64;    // key rows per tile
constexpr int DKP = 136;  // sK row pitch in halves (272 B; bank-spread)
constexpr int BKP = 72;   // sVT row pitch in halves (144 B; bank-spread)

// scale * log2(e): softmax in exp2 domain; folded into Q fragments at load.
#define CSC 0.12752863187087177f

static __device__ __forceinline__ f16x4 pk4(float x, float y, float z, float w) {
  auto a = __builtin_amdgcn_cvt_pkrtz(x, y);
  auto b = __builtin_amdgcn_cvt_pkrtz(z, w);
  f16x4 h;
  h[0] = (f16)a[0]; h[1] = (f16)a[1]; h[2] = (f16)b[0]; h[3] = (f16)b[1];
  return h;
}
static __device__ __forceinline__ f16x8 pk8(float4 u, float4 v) {
  f16x4 a = pk4(u.x, u.y, u.z, u.w);
  f16x4 b = pk4(v.x, v.y, v.z, v.w);
  f16x8 h;
  h[0] = a[0]; h[1] = a[1]; h[2] = a[2]; h[3] = a[3];
  h[4] = b[0]; h[5] = b[1]; h[6] = b[2]; h[7] = b[3];
  return h;
}
// pack two f32x4 (P values) to f16x8
static __device__ __forceinline__ f16x8 pk8v(f32x4 a, f32x4 b) {
  auto x0 = __builtin_amdgcn_cvt_pkrtz(a[0], a[1]);
  auto x1 = __builtin_amdgcn_cvt_pkrtz(a[2], a[3]);
  auto x2 = __builtin_amdgcn_cvt_pkrtz(b[0], b[1]);
  auto x3 = __builtin_amdgcn_cvt_pkrtz(b[2], b[3]);
  f16x8 h;
  h[0] = x0[0]; h[1] = x0[1]; h[2] = x1[0]; h[3] = x1[1];
  h[4] = x2[0]; h[5] = x2[1]; h[6] = x3[0]; h[7] = x3[1];
  return h;
}
// pack Q with CSC folded in
static __device__ __forceinline__ f16x8 pk8s(float4 u, float4 v) {
  float4 a = {u.x * CSC, u.y * CSC, u.z * CSC, u.w * CSC};
  float4 b = {v.x * CSC, v.y * CSC, v.z * CSC, v.w * CSC};
  return pk8(a, b);
}

// ---- staging-row permutation for sK (VERIFIED numerically in R4).
// Swapped QK^T (A = K): MFMA ct, A-position p = l16 holds actual key
//   key(ct,p) = (ct>>1)*32 + (p>>2)*8 + (ct&1)*4 + (p&3)
// so sv[ct][r] at lane(quad) is key = (ct>>1)*32 + quad*8 + (ct&1)*4 + r,
// which is EXACTLY the PV B-operand k-layout. Inverse (key kk -> LDS row):
static __device__ __forceinline__ int krp(int kk) {
  return ((kk >> 5) << 5) | (((kk >> 2) & 1) << 4) | (((kk >> 3) & 3) << 2) | (kk & 3);
}

// ---- issue global loads for tile T into reg set (KR,VR) — 256 threads
#define ISSUE(KR, VR, T)                                                   \
  do {                                                                     \
    const float4* Kt = (const float4*)(Kb + (size_t)(T) * BK * D);         \
    _Pragma("unroll")                                                      \
    for (int i_ = 0; i_ < 4; ++i_) {                                       \
      int cc_ = tid + i_ * 256;                                            \
      int row_ = cc_ >> 4, d04_ = (cc_ & 15) * 2;                          \
      KR[2 * i_]     = Kt[row_ * 32 + d04_];                               \
      KR[2 * i_ + 1] = Kt[row_ * 32 + d04_ + 1];                           \
    }                                                                      \
    const float* Vt = Vb + (size_t)(T) * BK * D;                           \
    _Pragma("unroll")                                                      \
    for (int i_ = 0; i_ < 2; ++i_) {                                       \
      int f_ = tid + i_ * 256;                                             \
      const float* base_ = Vt + (size_t)((f_ & 15) * 4) * D + (f_ >> 4) * 4; \
      VR[i_ * 4 + 0] = *(const float4*)(base_);                            \
      VR[i_ * 4 + 1] = *(const float4*)(base_ + D);                        \
      VR[i_ * 4 + 2] = *(const float4*)(base_ + 2 * D);                    \
      VR[i_ * 4 + 3] = *(const float4*)(base_ + 3 * D);                    \
    }                                                                      \
  } while (0)

// ---- convert+store reg set into LDS buffer NB
#define DRAIN(KR, VR, NB)                                                  \
  do {                                                                     \
    _Pragma("unroll")                                                      \
    for (int i_ = 0; i_ < 4; ++i_) {                                       \
      int cc_ = tid + i_ * 256;                                            \
      int row_ = cc_ >> 4, d0_ = (cc_ & 15) * 8;                           \
      *(f16x8*)&sK[NB][krp(row_)][d0_] = pk8(KR[2 * i_], KR[2 * i_ + 1]);  \
    }                                                                      \
    _Pragma("unroll")                                                      \
    for (int i_ = 0; i_ < 2; ++i_) {                                       \
      int f_ = tid + i_ * 256;                                             \
      int k0_ = (f_ & 15) * 4, d0_ = (f_ >> 4) * 4;                        \
      float4 r0_ = VR[i_*4+0], r1_ = VR[i_*4+1], r2_ = VR[i_*4+2], r3_ = VR[i_*4+3]; \
      *(f16x4*)&sVT[NB][d0_ + 0][k0_] = pk4(r0_.x, r1_.x, r2_.x, r3_.x);   \
      *(f16x4*)&sVT[NB][d0_ + 1][k0_] = pk4(r0_.y, r1_.y, r2_.y, r3_.y);   \
      *(f16x4*)&sVT[NB][d0_ + 2][k0_] = pk4(r0_.z, r1_.z, r2_.z, r3_.z);   \
      *(f16x4*)&sVT[NB][d0_ + 3][k0_] = pk4(r0_.w, r1_.w, r2_.w, r3_.w);   \
    }                                                                      \
  } while (0)

// raw barrier: lgkmcnt(0) for LDS visibility, NO forced vmcnt(0) drain
#define TILE_BARRIER()                                                     \
  do {                                                                     \
    asm volatile("s_waitcnt lgkmcnt(0)" ::: "memory");                     \
    __builtin_amdgcn_s_barrier();                                          \
    asm volatile("" ::: "memory");                                         \
  } while (0)

__global__ __launch_bounds__(256, 2)
void attn_fwd(const float* __restrict__ Qp, const float* __restrict__ Kp,
              const float* __restrict__ Vp, const int* __restrict__ VLp,
              float* __restrict__ Op) {
  // R4 post-mortem: BQ=128/1-block-per-CU collapsed TLP (1 wave/SIMD) and
  // broke LPT pairing (occupancy 14->6.2%) — regressed despite halved LDS
  // traffic. This version: R3 concurrency (512 blocks, 2 blocks/CU = 8
  // waves/CU, cheap+expensive pairing) + R4 per-wave wins (in-register
  // softmax via swapped operands — NO sP round-trip; CSC folded into Q;
  // mask only on partial tile; float4 epilogue). LDS 72 KB -> 2 blocks/CU.
  __shared__ f16 sK[2][BK][DKP];   // ROW-PERMUTED per krp() for swapped QK^T
  __shared__ f16 sVT[2][D][BKP];   // V tile transposed [d][kk]
  __shared__ int sN[32];
  __shared__ int sI[32];           // cost-rank -> batch

  const int tid  = threadIdx.x;
  const int wave = tid >> 6, lane = tid & 63;
  const int l16  = lane & 15, quad = lane >> 4;

  // ---- XCD-bound, LPT-balanced schedule (VERIFIED R1/R3: FETCH 81->17 MB).
  // 512 blocks: XCD = id&7; j=id>>3 in 0..63; jj=(j<32)?j:95-j pairs
  // (j, j+32) as (jj, 63-jj) -> CU pair gets rank slots (lr, 3-lr) =
  // cheap+expensive (LPT). Each XCD owns 4 batches {x,15-x,16+x,31-x}.
  if (tid < 32) sN[tid] = (VLp[tid] + BK - 1) / BK;
  __syncthreads();
  if (tid < 32) {
    int nb = sN[tid], r = 0;
    #pragma unroll
    for (int k = 0; k < 32; ++k) {
      int nk = sN[k];
      r += (nk > nb) || (nk == nb && k < tid);
    }
    sI[r] = tid;  // invert: rank -> batch
  }
  __syncthreads();
  const int xcd = blockIdx.x & 7;
  const int j   = (int)blockIdx.x >> 3;        // 0..63 within XCD
  const int jj  = (j < 32) ? j : (95 - j);     // pair (j, j+32) -> (jj, 63-jj)
  const int lr  = jj >> 4;                     // local rank slot 0..3
  const int qt  = jj & 15;
  const int grank = (lr == 0) ? xcd : (lr == 1) ? (15 - xcd)
                  : (lr == 2) ? (16 + xcd) : (31 - xcd);
  const int b  = sI[grank];
  const int vl = VLp[b];

  const float* Kb = Kp + (size_t)b * KL * D;
  const float* Vb = Vp + (size_t)b * KL * D;
  const int ntiles = (vl + BK - 1) / BK;

  // single staging reg set, distance-1 (R1: two sets spill; R3: spill-free)
  float4 kreg[8], vreg[8];

  // Q loads first (oldest in vmcnt order)
  const float* Qb = Qp + ((size_t)(b * QL + qt * BQ + wave * 16 + l16)) * D;
  float4 qtmp[8];
  #pragma unroll
  for (int kc = 0; kc < 4; ++kc) {
    const float* p = Qb + kc * 32 + quad * 8;
    qtmp[2 * kc]     = *(const float4*)p;
    qtmp[2 * kc + 1] = *(const float4*)(p + 4);
  }

  ISSUE(kreg, vreg, 0);

  // Q as B-operand fragments (col=q=l16, k=quad*8+j), CSC pre-folded
  f16x8 qf[4];
  #pragma unroll
  for (int kc = 0; kc < 4; ++kc) qf[kc] = pk8s(qtmp[2 * kc], qtmp[2 * kc + 1]);

  float m2 = -INFINITY, lsum = 0.f;
  f32x4 o[8];
  #pragma unroll
  for (int dt = 0; dt < 8; ++dt) o[dt] = (f32x4){0.f, 0.f, 0.f, 0.f};

  DRAIN(kreg, vreg, 0);
  TILE_BARRIER();

  for (int t = 0; t < ntiles; ++t) {
    const int cur = t & 1, nxt = cur ^ 1;
    const bool more = (t + 1 < ntiles);

    if (more) ISSUE(kreg, vreg, t + 1);

    // ---- S^T = K Q^T (swapped operands; per-wave 16 q's at q=l16)
    f32x4 sv[4];
    #pragma unroll
    for (int ct = 0; ct < 4; ++ct) {
      f32x4 cacc = (f32x4){0.f, 0.f, 0.f, 0.f};
      #pragma unroll
      for (int kc = 0; kc < 4; ++kc) {
        f16x8 kf = *(const f16x8*)&sK[cur][ct * 16 + l16][kc * 32 + quad * 8];
        cacc = __builtin_amdgcn_mfma_f32_16x16x32_f16(kf, qf[kc], cacc, 0, 0, 0);
      }
      sv[ct] = cacc;
    }

    // ---- key-padding mask, ONLY on the single partial tile (wave-uniform).
    // lane's key for (ct,r): t*64 + (ct>>1)*32 + (ct&1)*4 + quad*8 + r
    if (t * BK + BK > vl) {
      #pragma unroll
      for (int ct = 0; ct < 4; ++ct) {
        int kb = t * BK + (ct >> 1) * 32 + (ct & 1) * 4 + quad * 8;
        #pragma unroll
        for (int r = 0; r < 4; ++r)
          sv[ct][r] = (kb + r) < vl ? sv[ct][r] : -1.0e9f;
      }
    }

    // ---- online softmax, fully in-register (no sP round-trip)
    {
      float t0 = fmaxf(fmaxf(sv[0][0], sv[0][1]), fmaxf(sv[0][2], sv[0][3]));
      float t1 = fmaxf(fmaxf(sv[1][0], sv[1][1]), fmaxf(sv[1][2], sv[1][3]));
      float t2 = fmaxf(fmaxf(sv[2][0], sv[2][1]), fmaxf(sv[2][2], sv[2][3]));
      float t3 = fmaxf(fmaxf(sv[3][0], sv[3][1]), fmaxf(sv[3][2], sv[3][3]));
      float pmax = fmaxf(fmaxf(t0, t1), fmaxf(t2, t3));
      pmax = fmaxf(pmax, __shfl_xor(pmax, 16));
      pmax = fmaxf(pmax, __shfl_xor(pmax, 32));
      float mnew  = fmaxf(m2, pmax);
      float alpha = __builtin_amdgcn_exp2f(m2 - mnew);
      m2 = mnew;
      float ls = 0.f;
      #pragma unroll
      for (int ct = 0; ct < 4; ++ct) {
        #pragma unroll
        for (int r = 0; r < 4; ++r) {
          float p = __builtin_amdgcn_exp2f(sv[ct][r] - mnew);
          sv[ct][r] = p;
          ls += p;
        }
      }
      ls += __shfl_xor(ls, 16);
      ls += __shfl_xor(ls, 32);
      lsum = lsum * alpha + ls;
      #pragma unroll
      for (int dt = 0; dt < 8; ++dt) o[dt] *= alpha;
    }
    f16x8 pf0 = pk8v(sv[0], sv[1]);
    f16x8 pf1 = pk8v(sv[2], sv[3]);

    // ---- O^T += V^T P^T (P already in B-operand layout — no LDS, no wait)
    #pragma unroll
    for (int dt = 0; dt < 8; ++dt) {
      f16x8 vf0 = *(const f16x8*)&sVT[cur][dt * 16 + l16][quad * 8];
      o[dt] = __builtin_amdgcn_mfma_f32_16x16x32_f16(vf0, pf0, o[dt], 0, 0, 0);
      f16x8 vf1 = *(const f16x8*)&sVT[cur][dt * 16 + l16][32 + quad * 8];
      o[dt] = __builtin_amdgcn_mfma_f32_16x16x32_f16(vf1, pf1, o[dt], 0, 0, 0);
    }

    if (more) DRAIN(kreg, vreg, nxt);
    TILE_BARRIER();
  }

  // ---- epilogue: O = O^T/l. Lane holds O^T[d=dt*16+quad*4+r][q=l16];
  // 4 r-values are contiguous d -> float4 store.
  float* Ob = Op + ((size_t)(b * QL + qt * BQ + wave * 16)) * D;
  const float inv = 1.0f / lsum;
  #pragma unroll
  for (int dt = 0; dt < 8; ++dt) {
    float4 w = {o[dt][0] * inv, o[dt][1] * inv, o[dt][2] * inv, o[dt][3] * inv};
    *(float4*)&Ob[(size_t)l16 * D + dt * 16 + quad * 4] = w;
  }
}

extern "C" void kernel_launch(void* const* d_in, const int* in_sizes, int n_in,
                              void* d_out, int out_size, void* d_ws, size_t ws_size,
                              hipStream_t stream) {
  const float* Qp = (const float*)d_in[0];
  const float* Kp = (const float*)d_in[1];
  const float* Vp = (const float*)d_in[2];
  const int*   VL = (const int*)d_in[3];
  float* Op = (float*)d_out;

  attn_fwd<<<dim3(QL / BQ * BATCH), dim3(256), 0, stream>>>(Qp, Kp, Vp, VL, Op);
}